// Round 11
// baseline (256.212 us; speedup 1.0000x reference)
//
#include <hip/hip_runtime.h>

// B=512, N=256, F=512, H=512 ; rows = B*N = 131072
typedef unsigned short ushort_t;
using bf16x8 = __attribute__((ext_vector_type(8))) short;
using f32x4  = __attribute__((ext_vector_type(4))) float;
using us4    = __attribute__((ext_vector_type(4))) unsigned short;
using fl4    = __attribute__((ext_vector_type(4))) float;

// LDS/global swizzle: ushort index ^ ((row&7)<<3)  (== byte ^ ((row&7)<<4))
__device__ __forceinline__ int swz(int row) { return (row & 7) << 3; }

__device__ __forceinline__ unsigned short f2bf(float x) {
  unsigned int u = __float_as_uint(x);
  unsigned int r = u + 0x7FFFu + ((u >> 16) & 1u);   // round-to-nearest-even
  return (unsigned short)(r >> 16);
}
__device__ __forceinline__ float bf2f(unsigned short h) {
  return __uint_as_float(((unsigned int)h) << 16);
}
__device__ __forceinline__ void async16(void* lds, const void* g) {
  __builtin_amdgcn_global_load_lds(
      (const __attribute__((address_space(1))) unsigned int*)g,
      (__attribute__((address_space(3))) unsigned int*)lds, 16, 0, 0);
}
// fast tanh via hw exp + rcp: rel err ~1e-6, saturates correctly at +-inf
__device__ __forceinline__ float ftanh(float x) {
  float e = __expf(2.f * x);
  return 1.f - 2.f * __builtin_amdgcn_rcpf(e + 1.f);
}

// ---------------- prep: weight convert (pre-swizzled) / transpose ----------------
__global__ __launch_bounds__(256) void prep_kernel(
    const float* __restrict__ Wft, const float* __restrict__ Wf,
    const float* __restrict__ Wh,  const float* __restrict__ Ws,
    ushort_t* __restrict__ Wft_b, ushort_t* __restrict__ Wf_b,
    float* __restrict__ WhT, float* __restrict__ WsT) {
  int blk = blockIdx.x, t = threadIdx.x;
  if (blk < 128) {                       // Wft: 512*512 = 262144 elems
    int base = (blk * 256 + t) * 8;
    int n = base >> 9, k = base & 511;
    fl4 a = *(const fl4*)(Wft + base), b = *(const fl4*)(Wft + base + 4);
    us4 u0 = {f2bf(a[0]), f2bf(a[1]), f2bf(a[2]), f2bf(a[3])};
    us4 u1 = {f2bf(b[0]), f2bf(b[1]), f2bf(b[2]), f2bf(b[3])};
    int ks = k ^ swz(n);                 // swizzled store (8-aligned chunk stays contiguous)
    *(us4*)(Wft_b + n * 512 + ks) = u0; *(us4*)(Wft_b + n * 512 + ks + 4) = u1;
  } else if (blk < 192) {                // Wf: 256*512 = 131072 elems
    int base = ((blk - 128) * 256 + t) * 8;
    int n = base >> 9, k = base & 511;
    fl4 a = *(const fl4*)(Wf + base), b = *(const fl4*)(Wf + base + 4);
    us4 u0 = {f2bf(a[0]), f2bf(a[1]), f2bf(a[2]), f2bf(a[3])};
    us4 u1 = {f2bf(b[0]), f2bf(b[1]), f2bf(b[2]), f2bf(b[3])};
    int ks = k ^ swz(n);
    *(us4*)(Wf_b + n * 512 + ks) = u0; *(us4*)(Wf_b + n * 512 + ks + 4) = u1;
  } else {                               // transpose Wh, Ws: [256][512] -> [512][256]
    int base = ((blk - 192) * 256 + t) * 8;
    int n = base >> 9, k = base & 511;
#pragma unroll
    for (int j = 0; j < 8; j++) {
      WhT[(k + j) * 256 + n] = Wh[base + j];
      WsT[(k + j) * 256 + n] = Ws[base + j];
    }
  }
}

// ------- merged: blocks [0,256) = k0 (2 batches each); blocks [256,2304) = gemm1 -------
// gemm1 part: r2-proven BM=128, BN=256, BK=64; 512 thr = 8 waves (2r x 4c), 48 KB LDS,
// simple 2-barrier loop, A reg-staged f32->bf16, B via global_load_lds (pre-swizzled).
// k0 blocks co-reside with gemm1 blocks and fill their stall cycles.
// T5: s_setprio(1) around the MFMA cluster (heterogeneous co-resident waves -> the CU
// scheduler can favor compute-phase waves over staging-phase waves).
__global__ __launch_bounds__(512, 2) void fused_kernel(
    const float* __restrict__ feat, const ushort_t* __restrict__ Wft_b,
    const float* __restrict__ bft, ushort_t* __restrict__ ft,
    const float* __restrict__ hidden, const float* __restrict__ s_in,
    const float* __restrict__ WhT, const float* __restrict__ WsT,
    const float* __restrict__ bh, const float* __restrict__ bs,
    const float* __restrict__ Wc,
    float* __restrict__ h_g, float* __restrict__ i_sc) {
  __shared__ ushort_t As[128 * 64];     // 16 KB
  __shared__ ushort_t Bs[256 * 64];     // 32 KB
  __shared__ float hid2[2][512], sv2[2][512];  // 8 KB (k0 path)
  __shared__ float red[2][4];
  int tid = threadIdx.x;

  if (blockIdx.x < 256) {
    // ---------------- k0 path: 2 batches per block, 256 threads per batch ----------------
    int jb = tid >> 8, n = tid & 255;
    int b = blockIdx.x * 2 + jb;
    hid2[jb][n]       = hidden[b * 512 + n];
    hid2[jb][n + 256] = hidden[b * 512 + n + 256];
    sv2[jb][n]        = s_in[b * 512 + n];
    sv2[jb][n + 256]  = s_in[b * 512 + n + 256];
    __syncthreads();
    float ah = 0.f, aw = 0.f;
#pragma unroll 8
    for (int k = 0; k < 512; k++) {
      ah = fmaf(hid2[jb][k], WhT[k * 256 + n], ah);
      aw = fmaf(sv2[jb][k],  WsT[k * 256 + n], aw);
    }
    float h = ah + bh[n];
    h_g[b * 256 + n] = h;
    float w = ftanh(aw + bs[n] + h);
    float p = w * Wc[n];
#pragma unroll
    for (int off = 32; off >= 1; off >>= 1) p += __shfl_xor(p, off);
    if ((tid & 63) == 0) red[jb][(tid >> 6) & 3] = p;
    __syncthreads();
    if ((tid & 255) == 0)                 // tid==0 and tid==256
      i_sc[b] = red[jb][0] + red[jb][1] + red[jb][2] + red[jb][3];  // bc cancels in softmax
    return;
  }

  // ---------------- gemm1 path ----------------
  int i = blockIdx.x - 256;
  // XCD-chunked remap: tn pairs adjacent so a tm's 2 tn-blocks share the A-panel in L2
  int virt = (i & 7) * 256 + (i >> 3);
  int tm = virt >> 1, tn = virt & 1;
  int lane = tid & 63, w = tid >> 6;
  int wr = w & 1, wc = w >> 1;            // 2 x 4
  f32x4 acc[4][4] = {};
  const float* Ab = feat + (size_t)tm * 128 * 512;
  const ushort_t* Bb = Wft_b + (size_t)tn * 256 * 512;   // pre-swizzled layout
  for (int ks = 0; ks < 8; ks++) {
#pragma unroll
    for (int c = 0; c < 4; c++) {        // B: global_load_lds (global pre-swizzled, LDS linear)
      int flat = c * 4096 + tid * 8;
      int row = flat >> 6, k = flat & 63;
      async16(&Bs[flat], Bb + (size_t)row * 512 + ks * 64 + k);
    }
#pragma unroll
    for (int c = 0; c < 4; c++) {        // A: reg-stage f32 -> bf16, swizzled ds_write
      int flat = c * 2048 + tid * 4;
      int row = flat >> 6, col = flat & 63;
      fl4 v = *(const fl4*)(Ab + (size_t)row * 512 + ks * 64 + col);
      us4 u = {f2bf(v[0]), f2bf(v[1]), f2bf(v[2]), f2bf(v[3])};
      *(us4*)&As[flat ^ swz(row)] = u;
    }
    __syncthreads();
    __builtin_amdgcn_s_setprio(1);
#pragma unroll
    for (int kk = 0; kk < 2; kk++) {
      bf16x8 afr[4], bfr[4];
#pragma unroll
      for (int m = 0; m < 4; m++) {
        int row = wr * 64 + m * 16 + (lane & 15);
        int off = kk * 32 + (lane >> 4) * 8;
        afr[m] = *(const bf16x8*)&As[row * 64 + (off ^ swz(row))];
      }
#pragma unroll
      for (int n = 0; n < 4; n++) {
        int row = wc * 64 + n * 16 + (lane & 15);
        int off = kk * 32 + (lane >> 4) * 8;
        bfr[n] = *(const bf16x8*)&Bs[row * 64 + (off ^ swz(row))];
      }
#pragma unroll
      for (int m = 0; m < 4; m++)
#pragma unroll
        for (int n = 0; n < 4; n++)
          acc[m][n] = __builtin_amdgcn_mfma_f32_16x16x32_bf16(afr[m], bfr[n], acc[m][n], 0, 0, 0);
    }
    __builtin_amdgcn_s_setprio(0);
    __syncthreads();
  }
  int r0 = tm * 128 + wr * 64 + (lane >> 4) * 4;
  int c0 = tn * 256 + wc * 64 + (lane & 15);
#pragma unroll
  for (int n = 0; n < 4; n++) {
    int col = c0 + n * 16;
    float bias = bft[col];
#pragma unroll
    for (int m = 0; m < 4; m++) {
      int row = r0 + m * 16;
#pragma unroll
      for (int v = 0; v < 4; v++) {
        float val = fmaxf(acc[m][n][v] + bias, 0.f);
        int gr = row + v;
        ft[(size_t)gr * 512 + (col ^ swz(gr))] = f2bf(val);   // swizzled store
      }
    }
  }
}

// ---------------- gemm2: per-batch f=ft@Wf^T fused with z/softmax/c/gate ----------------
__global__ __launch_bounds__(512, 2) void gemm2_kernel(
    const ushort_t* __restrict__ ft, const ushort_t* __restrict__ Wf_b,
    const float* __restrict__ bf, const float* __restrict__ h_g,
    const float* __restrict__ Wc, const float* __restrict__ i_sc,
    const float* __restrict__ s_in, float* __restrict__ out) {
  __shared__ ushort_t As[2][256 * 64];   // 64 KB
  __shared__ ushort_t Bs[2][256 * 64];   // 64 KB
  __shared__ float hb[256], wcl[256];
  __shared__ float z2[2][256];
  __shared__ float al[256];
  __shared__ float cpar[4][512];         // 8 KB
  __shared__ float bg_sh;
  int b = blockIdx.x, tid = threadIdx.x;  // 512 threads, 8 waves
  int lane = tid & 63, w = tid >> 6;
  int wr = w >> 1, wc = w & 1;            // 4 row-groups x 2 col-groups
  if (tid < 256) { hb[tid] = h_g[b * 256 + tid] + bf[tid]; wcl[tid] = Wc[tid]; }
  f32x4 acc[4][8] = {};
  const ushort_t* Ab = ft + (size_t)b * 256 * 512;   // pre-swizzled layout

  // ---- prologue: stage tile 0 ----
#pragma unroll
  for (int c = 0; c < 4; c++) {
    int flat = c * 4096 + tid * 8;
    int row = flat >> 6, k = flat & 63;
    async16(&As[0][flat], Ab + (size_t)row * 512 + k);
    async16(&Bs[0][flat], Wf_b + (size_t)row * 512 + k);
  }
  __syncthreads();

  for (int t = 0; t < 8; t++) {
    int cur = t & 1, nxt = cur ^ 1;
    if (t < 7) {
#pragma unroll
      for (int c = 0; c < 4; c++) {
        int flat = c * 4096 + tid * 8;
        int row = flat >> 6, k = flat & 63;
        async16(&As[nxt][flat], Ab + (size_t)row * 512 + (t + 1) * 64 + k);
        async16(&Bs[nxt][flat], Wf_b + (size_t)row * 512 + (t + 1) * 64 + k);
      }
    }
    __builtin_amdgcn_sched_barrier(0);
    __builtin_amdgcn_s_setprio(1);
#pragma unroll
    for (int kk = 0; kk < 2; kk++) {
      bf16x8 afr[4], bfr[8];
#pragma unroll
      for (int m = 0; m < 4; m++) {
        int row = wr * 64 + m * 16 + (lane & 15);
        int off = kk * 32 + (lane >> 4) * 8;
        afr[m] = *(const bf16x8*)&As[cur][row * 64 + (off ^ swz(row))];
      }
#pragma unroll
      for (int n = 0; n < 8; n++) {
        int row = wc * 128 + n * 16 + (lane & 15);
        int off = kk * 32 + (lane >> 4) * 8;
        bfr[n] = *(const bf16x8*)&Bs[cur][row * 64 + (off ^ swz(row))];
      }
#pragma unroll
      for (int m = 0; m < 4; m++)
#pragma unroll
        for (int n = 0; n < 8; n++)
          acc[m][n] = __builtin_amdgcn_mfma_f32_16x16x32_bf16(afr[m], bfr[n], acc[m][n], 0, 0, 0);
    }
    __builtin_amdgcn_s_setprio(0);
    __syncthreads();
  }
  // z[b, row] = sum_col tanh(f + h[col] + bf[col]) * Wc[col]
#pragma unroll
  for (int m = 0; m < 4; m++) {
#pragma unroll
    for (int v = 0; v < 4; v++) {
      float p = 0.f;
#pragma unroll
      for (int n = 0; n < 8; n++) {
        int col = wc * 128 + n * 16 + (lane & 15);
        p += ftanh(acc[m][n][v] + hb[col]) * wcl[col];
      }
      p += __shfl_xor(p, 1); p += __shfl_xor(p, 2);
      p += __shfl_xor(p, 4); p += __shfl_xor(p, 8);
      if ((lane & 15) == 0)
        z2[wc][wr * 64 + m * 16 + (lane >> 4) * 4 + v] = p;
    }
  }
  __syncthreads();
  if (tid < 64) {                         // softmax over 256 z (+ i_score concat gate)
    float zv[4], e[4];
    float M = -3.4e38f;
#pragma unroll
    for (int j = 0; j < 4; j++) { zv[j] = z2[0][tid + 64 * j] + z2[1][tid + 64 * j]; M = fmaxf(M, zv[j]); }
#pragma unroll
    for (int off = 32; off >= 1; off >>= 1) M = fmaxf(M, __shfl_xor(M, off));
    float ssum = 0.f;
#pragma unroll
    for (int j = 0; j < 4; j++) { e[j] = __expf(zv[j] - M); ssum += e[j]; }
#pragma unroll
    for (int off = 32; off >= 1; off >>= 1) ssum += __shfl_xor(ssum, off);
    float inv = 1.f / ssum;
#pragma unroll
    for (int j = 0; j < 4; j++) al[tid + 64 * j] = e[j] * inv;
    if (tid == 0) {
      float isc = i_sc[b];
      float M2 = fmaxf(M, isc);
      float den = ssum * __expf(M - M2) + __expf(isc - M2);
      bg_sh = __expf(isc - M2) / den;
    }
  }
  __syncthreads();
  // c[h] = sum_n a[n] * ft[b,n,h]; vectorized: thread = (n-group g, col-quad q)
  {
    int q = tid & 127;                    // cols q*4 .. q*4+3
    int g = tid >> 7;                     // n in [g*64, g*64+64)
    f32x4 cs = {0.f, 0.f, 0.f, 0.f};
#pragma unroll 4
    for (int j = 0; j < 64; j++) {
      int n = g * 64 + j;
      float a = al[n];
      us4 v = *(const us4*)&Ab[(size_t)n * 512 + ((q * 4) ^ swz(n))];
      cs[0] = fmaf(a, bf2f(v[0]), cs[0]);
      cs[1] = fmaf(a, bf2f(v[1]), cs[1]);
      cs[2] = fmaf(a, bf2f(v[2]), cs[2]);
      cs[3] = fmaf(a, bf2f(v[3]), cs[3]);
    }
    *(f32x4*)&cpar[g][q * 4] = cs;
  }
  __syncthreads();
  {
    float cv = cpar[0][tid] + cpar[1][tid] + cpar[2][tid] + cpar[3][tid];
    float bg = bg_sh;
    out[b * 512 + tid] = bg * s_in[b * 512 + tid] + (1.f - bg) * cv;
  }
}

extern "C" void kernel_launch(void* const* d_in, const int* in_sizes, int n_in,
                              void* d_out, int out_size, void* d_ws, size_t ws_size,
                              hipStream_t stream) {
  const float* features = (const float*)d_in[0];
  const float* hidden   = (const float*)d_in[1];
  const float* s_in     = (const float*)d_in[4];
  const float* Wft      = (const float*)d_in[5];
  const float* bft      = (const float*)d_in[6];
  const float* Wf       = (const float*)d_in[7];
  const float* bf       = (const float*)d_in[8];
  const float* Wh       = (const float*)d_in[9];
  const float* bh       = (const float*)d_in[10];
  const float* Wc       = (const float*)d_in[11];
  const float* Ws       = (const float*)d_in[13];
  const float* bs       = (const float*)d_in[14];
  float* out = (float*)d_out;

  unsigned char* p = (unsigned char*)d_ws;
  ushort_t* ft    = (ushort_t*)p;  p += (size_t)131072 * 512 * 2;  // 134 MB
  ushort_t* Wft_b = (ushort_t*)p;  p += 512 * 512 * 2;
  ushort_t* Wf_b  = (ushort_t*)p;  p += 256 * 512 * 2;
  float* WhT      = (float*)p;     p += 512 * 256 * 4;
  float* WsT      = (float*)p;     p += 512 * 256 * 4;
  float* h_g      = (float*)p;     p += 512 * 256 * 4;
  float* i_sc     = (float*)p;     p += 512 * 4;

  prep_kernel<<<256, 256, 0, stream>>>(Wft, Wf, Wh, Ws, Wft_b, Wf_b, WhT, WsT);
  fused_kernel<<<2304, 512, 0, stream>>>(features, Wft_b, bft, ft,
                                         hidden, s_in, WhT, WsT, bh, bs, Wc, h_g, i_sc);
  gemm2_kernel<<<512, 512, 0, stream>>>(ft, Wf_b, bf, h_g, Wc, i_sc, s_in, out);
}

// Round 12
// 219.783 us; speedup vs baseline: 1.1657x; 1.1657x over previous
//
#include <hip/hip_runtime.h>

// B=512, N=256, F=512, H=512 ; rows = B*N = 131072
typedef unsigned short ushort_t;
using bf16x8 = __attribute__((ext_vector_type(8))) short;
using f32x4  = __attribute__((ext_vector_type(4))) float;
using us4    = __attribute__((ext_vector_type(4))) unsigned short;
using fl4    = __attribute__((ext_vector_type(4))) float;

// LDS/global swizzle: ushort index ^ ((row&7)<<3)  (== byte ^ ((row&7)<<4))
__device__ __forceinline__ int swz(int row) { return (row & 7) << 3; }

__device__ __forceinline__ unsigned short f2bf(float x) {
  unsigned int u = __float_as_uint(x);
  unsigned int r = u + 0x7FFFu + ((u >> 16) & 1u);   // round-to-nearest-even
  return (unsigned short)(r >> 16);
}
__device__ __forceinline__ float bf2f(unsigned short h) {
  return __uint_as_float(((unsigned int)h) << 16);
}
__device__ __forceinline__ void async16(void* lds, const void* g) {
  __builtin_amdgcn_global_load_lds(
      (const __attribute__((address_space(1))) unsigned int*)g,
      (__attribute__((address_space(3))) unsigned int*)lds, 16, 0, 0);
}
// fast tanh via hw exp + rcp: rel err ~1e-6, saturates correctly at +-inf
__device__ __forceinline__ float ftanh(float x) {
  float e = __expf(2.f * x);
  return 1.f - 2.f * __builtin_amdgcn_rcpf(e + 1.f);
}

// ---------------- prep: weight convert (pre-swizzled) / transpose ----------------
__global__ __launch_bounds__(256) void prep_kernel(
    const float* __restrict__ Wft, const float* __restrict__ Wf,
    const float* __restrict__ Wh,  const float* __restrict__ Ws,
    ushort_t* __restrict__ Wft_b, ushort_t* __restrict__ Wf_b,
    float* __restrict__ WhT, float* __restrict__ WsT) {
  int blk = blockIdx.x, t = threadIdx.x;
  if (blk < 128) {                       // Wft: 512*512 = 262144 elems
    int base = (blk * 256 + t) * 8;
    int n = base >> 9, k = base & 511;
    fl4 a = *(const fl4*)(Wft + base), b = *(const fl4*)(Wft + base + 4);
    us4 u0 = {f2bf(a[0]), f2bf(a[1]), f2bf(a[2]), f2bf(a[3])};
    us4 u1 = {f2bf(b[0]), f2bf(b[1]), f2bf(b[2]), f2bf(b[3])};
    int ks = k ^ swz(n);                 // swizzled store (8-aligned chunk stays contiguous)
    *(us4*)(Wft_b + n * 512 + ks) = u0; *(us4*)(Wft_b + n * 512 + ks + 4) = u1;
  } else if (blk < 192) {                // Wf: 256*512 = 131072 elems
    int base = ((blk - 128) * 256 + t) * 8;
    int n = base >> 9, k = base & 511;
    fl4 a = *(const fl4*)(Wf + base), b = *(const fl4*)(Wf + base + 4);
    us4 u0 = {f2bf(a[0]), f2bf(a[1]), f2bf(a[2]), f2bf(a[3])};
    us4 u1 = {f2bf(b[0]), f2bf(b[1]), f2bf(b[2]), f2bf(b[3])};
    int ks = k ^ swz(n);
    *(us4*)(Wf_b + n * 512 + ks) = u0; *(us4*)(Wf_b + n * 512 + ks + 4) = u1;
  } else {                               // transpose Wh, Ws: [256][512] -> [512][256]
    int base = ((blk - 192) * 256 + t) * 8;
    int n = base >> 9, k = base & 511;
#pragma unroll
    for (int j = 0; j < 8; j++) {
      WhT[(k + j) * 256 + n] = Wh[base + j];
      WsT[(k + j) * 256 + n] = Ws[base + j];
    }
  }
}

// ------- merged: blocks [0,256) = k0 (2 batches each); blocks [256,2304) = gemm1 -------
// gemm1 part: r2-proven BM=128, BN=256, BK=64; 512 thr = 8 waves (2r x 4c), 48 KB LDS,
// simple 2-barrier loop, A reg-staged f32->bf16, B via global_load_lds (pre-swizzled).
// k0 blocks co-reside with gemm1 blocks and fill their stall cycles (free ~15 us).
__global__ __launch_bounds__(512, 2) void fused_kernel(
    const float* __restrict__ feat, const ushort_t* __restrict__ Wft_b,
    const float* __restrict__ bft, ushort_t* __restrict__ ft,
    const float* __restrict__ hidden, const float* __restrict__ s_in,
    const float* __restrict__ WhT, const float* __restrict__ WsT,
    const float* __restrict__ bh, const float* __restrict__ bs,
    const float* __restrict__ Wc,
    float* __restrict__ h_g, float* __restrict__ i_sc) {
  __shared__ ushort_t As[128 * 64];     // 16 KB
  __shared__ ushort_t Bs[256 * 64];     // 32 KB
  __shared__ float hid2[2][512], sv2[2][512];  // 8 KB (k0 path)
  __shared__ float red[2][4];
  int tid = threadIdx.x;

  if (blockIdx.x < 256) {
    // ---------------- k0 path: 2 batches per block, 256 threads per batch ----------------
    int jb = tid >> 8, n = tid & 255;
    int b = blockIdx.x * 2 + jb;
    hid2[jb][n]       = hidden[b * 512 + n];
    hid2[jb][n + 256] = hidden[b * 512 + n + 256];
    sv2[jb][n]        = s_in[b * 512 + n];
    sv2[jb][n + 256]  = s_in[b * 512 + n + 256];
    __syncthreads();
    float ah = 0.f, aw = 0.f;
#pragma unroll 8
    for (int k = 0; k < 512; k++) {
      ah = fmaf(hid2[jb][k], WhT[k * 256 + n], ah);
      aw = fmaf(sv2[jb][k],  WsT[k * 256 + n], aw);
    }
    float h = ah + bh[n];
    h_g[b * 256 + n] = h;
    float w = ftanh(aw + bs[n] + h);
    float p = w * Wc[n];
#pragma unroll
    for (int off = 32; off >= 1; off >>= 1) p += __shfl_xor(p, off);
    if ((tid & 63) == 0) red[jb][(tid >> 6) & 3] = p;
    __syncthreads();
    if ((tid & 255) == 0)                 // tid==0 and tid==256
      i_sc[b] = red[jb][0] + red[jb][1] + red[jb][2] + red[jb][3];  // bc cancels in softmax
    return;
  }

  // ---------------- gemm1 path ----------------
  int i = blockIdx.x - 256;
  // XCD-chunked remap: tn pairs adjacent so a tm's 2 tn-blocks share the A-panel in L2
  int virt = (i & 7) * 256 + (i >> 3);
  int tm = virt >> 1, tn = virt & 1;
  int lane = tid & 63, w = tid >> 6;
  int wr = w & 1, wc = w >> 1;            // 2 x 4
  f32x4 acc[4][4] = {};
  const float* Ab = feat + (size_t)tm * 128 * 512;
  const ushort_t* Bb = Wft_b + (size_t)tn * 256 * 512;   // pre-swizzled layout
  for (int ks = 0; ks < 8; ks++) {
#pragma unroll
    for (int c = 0; c < 4; c++) {        // B: global_load_lds (global pre-swizzled, LDS linear)
      int flat = c * 4096 + tid * 8;
      int row = flat >> 6, k = flat & 63;
      async16(&Bs[flat], Bb + (size_t)row * 512 + ks * 64 + k);
    }
#pragma unroll
    for (int c = 0; c < 4; c++) {        // A: reg-stage f32 -> bf16, swizzled ds_write
      int flat = c * 2048 + tid * 4;
      int row = flat >> 6, col = flat & 63;
      fl4 v = *(const fl4*)(Ab + (size_t)row * 512 + ks * 64 + col);
      us4 u = {f2bf(v[0]), f2bf(v[1]), f2bf(v[2]), f2bf(v[3])};
      *(us4*)&As[flat ^ swz(row)] = u;
    }
    __syncthreads();
#pragma unroll
    for (int kk = 0; kk < 2; kk++) {
      bf16x8 afr[4], bfr[4];
#pragma unroll
      for (int m = 0; m < 4; m++) {
        int row = wr * 64 + m * 16 + (lane & 15);
        int off = kk * 32 + (lane >> 4) * 8;
        afr[m] = *(const bf16x8*)&As[row * 64 + (off ^ swz(row))];
      }
#pragma unroll
      for (int n = 0; n < 4; n++) {
        int row = wc * 64 + n * 16 + (lane & 15);
        int off = kk * 32 + (lane >> 4) * 8;
        bfr[n] = *(const bf16x8*)&Bs[row * 64 + (off ^ swz(row))];
      }
#pragma unroll
      for (int m = 0; m < 4; m++)
#pragma unroll
        for (int n = 0; n < 4; n++)
          acc[m][n] = __builtin_amdgcn_mfma_f32_16x16x32_bf16(afr[m], bfr[n], acc[m][n], 0, 0, 0);
    }
    __syncthreads();
  }
  int r0 = tm * 128 + wr * 64 + (lane >> 4) * 4;
  int c0 = tn * 256 + wc * 64 + (lane & 15);
#pragma unroll
  for (int n = 0; n < 4; n++) {
    int col = c0 + n * 16;
    float bias = bft[col];
#pragma unroll
    for (int m = 0; m < 4; m++) {
      int row = r0 + m * 16;
#pragma unroll
      for (int v = 0; v < 4; v++) {
        float val = fmaxf(acc[m][n][v] + bias, 0.f);
        int gr = row + v;
        ft[(size_t)gr * 512 + (col ^ swz(gr))] = f2bf(val);   // swizzled store
      }
    }
  }
}

// ---------------- gemm2: per-batch f=ft@Wf^T fused with z/softmax/c/gate ----------------
__global__ __launch_bounds__(512, 2) void gemm2_kernel(
    const ushort_t* __restrict__ ft, const ushort_t* __restrict__ Wf_b,
    const float* __restrict__ bf, const float* __restrict__ h_g,
    const float* __restrict__ Wc, const float* __restrict__ i_sc,
    const float* __restrict__ s_in, float* __restrict__ out) {
  __shared__ ushort_t As[2][256 * 64];   // 64 KB
  __shared__ ushort_t Bs[2][256 * 64];   // 64 KB
  __shared__ float hb[256], wcl[256];
  __shared__ float z2[2][256];
  __shared__ float al[256];
  __shared__ float cpar[4][512];         // 8 KB
  __shared__ float bg_sh;
  int b = blockIdx.x, tid = threadIdx.x;  // 512 threads, 8 waves
  int lane = tid & 63, w = tid >> 6;
  int wr = w >> 1, wc = w & 1;            // 4 row-groups x 2 col-groups
  if (tid < 256) { hb[tid] = h_g[b * 256 + tid] + bf[tid]; wcl[tid] = Wc[tid]; }
  f32x4 acc[4][8] = {};
  const ushort_t* Ab = ft + (size_t)b * 256 * 512;   // pre-swizzled layout

  // ---- prologue: stage tile 0 ----
#pragma unroll
  for (int c = 0; c < 4; c++) {
    int flat = c * 4096 + tid * 8;
    int row = flat >> 6, k = flat & 63;
    async16(&As[0][flat], Ab + (size_t)row * 512 + k);
    async16(&Bs[0][flat], Wf_b + (size_t)row * 512 + k);
  }
  __syncthreads();

  for (int t = 0; t < 8; t++) {
    int cur = t & 1, nxt = cur ^ 1;
    if (t < 7) {
#pragma unroll
      for (int c = 0; c < 4; c++) {
        int flat = c * 4096 + tid * 8;
        int row = flat >> 6, k = flat & 63;
        async16(&As[nxt][flat], Ab + (size_t)row * 512 + (t + 1) * 64 + k);
        async16(&Bs[nxt][flat], Wf_b + (size_t)row * 512 + (t + 1) * 64 + k);
      }
    }
    __builtin_amdgcn_sched_barrier(0);
#pragma unroll
    for (int kk = 0; kk < 2; kk++) {
      bf16x8 afr[4], bfr[8];
#pragma unroll
      for (int m = 0; m < 4; m++) {
        int row = wr * 64 + m * 16 + (lane & 15);
        int off = kk * 32 + (lane >> 4) * 8;
        afr[m] = *(const bf16x8*)&As[cur][row * 64 + (off ^ swz(row))];
      }
#pragma unroll
      for (int n = 0; n < 8; n++) {
        int row = wc * 128 + n * 16 + (lane & 15);
        int off = kk * 32 + (lane >> 4) * 8;
        bfr[n] = *(const bf16x8*)&Bs[cur][row * 64 + (off ^ swz(row))];
      }
#pragma unroll
      for (int m = 0; m < 4; m++)
#pragma unroll
        for (int n = 0; n < 8; n++)
          acc[m][n] = __builtin_amdgcn_mfma_f32_16x16x32_bf16(afr[m], bfr[n], acc[m][n], 0, 0, 0);
    }
    __syncthreads();
  }
  // z[b, row] = sum_col tanh(f + h[col] + bf[col]) * Wc[col]
#pragma unroll
  for (int m = 0; m < 4; m++) {
#pragma unroll
    for (int v = 0; v < 4; v++) {
      float p = 0.f;
#pragma unroll
      for (int n = 0; n < 8; n++) {
        int col = wc * 128 + n * 16 + (lane & 15);
        p += ftanh(acc[m][n][v] + hb[col]) * wcl[col];
      }
      p += __shfl_xor(p, 1); p += __shfl_xor(p, 2);
      p += __shfl_xor(p, 4); p += __shfl_xor(p, 8);
      if ((lane & 15) == 0)
        z2[wc][wr * 64 + m * 16 + (lane >> 4) * 4 + v] = p;
    }
  }
  __syncthreads();
  if (tid < 64) {                         // softmax over 256 z (+ i_score concat gate)
    float zv[4], e[4];
    float M = -3.4e38f;
#pragma unroll
    for (int j = 0; j < 4; j++) { zv[j] = z2[0][tid + 64 * j] + z2[1][tid + 64 * j]; M = fmaxf(M, zv[j]); }
#pragma unroll
    for (int off = 32; off >= 1; off >>= 1) M = fmaxf(M, __shfl_xor(M, off));
    float ssum = 0.f;
#pragma unroll
    for (int j = 0; j < 4; j++) { e[j] = __expf(zv[j] - M); ssum += e[j]; }
#pragma unroll
    for (int off = 32; off >= 1; off >>= 1) ssum += __shfl_xor(ssum, off);
    float inv = 1.f / ssum;
#pragma unroll
    for (int j = 0; j < 4; j++) al[tid + 64 * j] = e[j] * inv;
    if (tid == 0) {
      float isc = i_sc[b];
      float M2 = fmaxf(M, isc);
      float den = ssum * __expf(M - M2) + __expf(isc - M2);
      bg_sh = __expf(isc - M2) / den;
    }
  }
  __syncthreads();
  // c[h] = sum_n a[n] * ft[b,n,h]; vectorized: thread = (n-group g, col-quad q)
  {
    int q = tid & 127;                    // cols q*4 .. q*4+3
    int g = tid >> 7;                     // n in [g*64, g*64+64)
    f32x4 cs = {0.f, 0.f, 0.f, 0.f};
#pragma unroll 4
    for (int j = 0; j < 64; j++) {
      int n = g * 64 + j;
      float a = al[n];
      us4 v = *(const us4*)&Ab[(size_t)n * 512 + ((q * 4) ^ swz(n))];
      cs[0] = fmaf(a, bf2f(v[0]), cs[0]);
      cs[1] = fmaf(a, bf2f(v[1]), cs[1]);
      cs[2] = fmaf(a, bf2f(v[2]), cs[2]);
      cs[3] = fmaf(a, bf2f(v[3]), cs[3]);
    }
    *(f32x4*)&cpar[g][q * 4] = cs;
  }
  __syncthreads();
  {
    float cv = cpar[0][tid] + cpar[1][tid] + cpar[2][tid] + cpar[3][tid];
    float bg = bg_sh;
    out[b * 512 + tid] = bg * s_in[b * 512 + tid] + (1.f - bg) * cv;
  }
}

extern "C" void kernel_launch(void* const* d_in, const int* in_sizes, int n_in,
                              void* d_out, int out_size, void* d_ws, size_t ws_size,
                              hipStream_t stream) {
  const float* features = (const float*)d_in[0];
  const float* hidden   = (const float*)d_in[1];
  const float* s_in     = (const float*)d_in[4];
  const float* Wft      = (const float*)d_in[5];
  const float* bft      = (const float*)d_in[6];
  const float* Wf       = (const float*)d_in[7];
  const float* bf       = (const float*)d_in[8];
  const float* Wh       = (const float*)d_in[9];
  const float* bh       = (const float*)d_in[10];
  const float* Wc       = (const float*)d_in[11];
  const float* Ws       = (const float*)d_in[13];
  const float* bs       = (const float*)d_in[14];
  float* out = (float*)d_out;

  unsigned char* p = (unsigned char*)d_ws;
  ushort_t* ft    = (ushort_t*)p;  p += (size_t)131072 * 512 * 2;  // 134 MB
  ushort_t* Wft_b = (ushort_t*)p;  p += 512 * 512 * 2;
  ushort_t* Wf_b  = (ushort_t*)p;  p += 256 * 512 * 2;
  float* WhT      = (float*)p;     p += 512 * 256 * 4;
  float* WsT      = (float*)p;     p += 512 * 256 * 4;
  float* h_g      = (float*)p;     p += 512 * 256 * 4;
  float* i_sc     = (float*)p;     p += 512 * 4;

  prep_kernel<<<256, 256, 0, stream>>>(Wft, Wf, Wh, Ws, Wft_b, Wf_b, WhT, WsT);
  fused_kernel<<<2304, 512, 0, stream>>>(features, Wft_b, bft, ft,
                                         hidden, s_in, WhT, WsT, bh, bs, Wc, h_g, i_sc);
  gemm2_kernel<<<512, 512, 0, stream>>>(ft, Wf_b, bf, h_g, Wc, i_sc, s_in, out);
}